// Round 1
// baseline (802.253 us; speedup 1.0000x reference)
//
#include <hip/hip_runtime.h>
#include <math.h>

// ---------------- problem constants ----------------
#define DD 2048
#define NBANK 65536

// ---------------- ws layout (float-element offsets, all 16-float aligned) ----
constexpr int WS_SIMS   = 0;        // 65536 floats
constexpr int WS_CVAL   = 65536;    // 2048 floats (stage-1 top-8 candidate values)
constexpr int WS_CIDX   = 67584;    // 2048 ints   (candidate indices)
constexpr int WS_TOPIDX = 69632;    // 16 ints     (final top-8 indices)
constexpr int WS_U      = 69648;    // 2048 floats (u = q_vec * ws)
constexpr int WS_V      = 71696;    // 2048 floats (v = Wc @ u)
constexpr int WS_CMAT   = 73744;    // 12*2048 floats (C matrix)
constexpr int WS_LOGITS = 98320;    // 16 floats
constexpr int WS_QACC   = 98336;    // 2048 (atomic acc for ctx@Wq)   } contiguous
constexpr int WS_HGACC  = 100384;   // 2048 (atomic acc for ctx@Wg1)  } memset
constexpr int WS_MACC   = 102432;   // 2048 (atomic acc for s_raw@Wm) } region
constexpr int WS_GACC   = 104480;   // 1    (gate scalar acc)         }
constexpr int WS_BCU    = 104481;   // 1    (bc . u scalar acc)       }

// =====================================================================
// MEGA1: blocks [0,16384): sims[row] = dot(mem[row],z)/||mem[row]||  (wave/row)
//        blocks [16384,16640): split-K GEMV for ctx@Wq and ctx@Wg1 (atomics)
// =====================================================================
__global__ __launch_bounds__(256) void k_mega1(
    const float* __restrict__ z, const float* __restrict__ h,
    const float* __restrict__ mem, const float* __restrict__ Wq,
    const float* __restrict__ Wg1, float* __restrict__ ws)
{
  int bid = blockIdx.x;
  int tid = threadIdx.x;
  if (bid < 16384) {
    int wv = tid >> 6, lane = tid & 63;
    int row = bid * 4 + wv;
    const float4* mrow = (const float4*)(mem + (size_t)row * DD);
    const float4* z4   = (const float4*)z;
    float dot = 0.f, ss = 0.f;
#pragma unroll
    for (int it = 0; it < 8; ++it) {
      float4 m4 = mrow[lane + 64 * it];
      float4 zz = z4[lane + 64 * it];
      dot += m4.x * zz.x + m4.y * zz.y + m4.z * zz.z + m4.w * zz.w;
      ss  += m4.x * m4.x + m4.y * m4.y + m4.z * m4.z + m4.w * m4.w;
    }
    for (int off = 32; off > 0; off >>= 1) {
      dot += __shfl_down(dot, off);
      ss  += __shfl_down(ss, off);
    }
    if (lane == 0)
      ws[WS_SIMS + row] = dot / fmaxf(sqrtf(ss), 1e-12f);
  } else {
    int b2 = bid - 16384;
    const float* W = (b2 < 128) ? Wq : Wg1;
    float* acc = ws + ((b2 < 128) ? WS_QACC : WS_HGACC);
    int g  = b2 & 127;
    int jt = g & 1;        // 2 j-tiles of 1024 cols
    int kc = g >> 1;       // 64 k-chunks of 64 rows (K = 4096)
    int j  = jt * 1024 + tid * 4;
    float4 a = {0.f, 0.f, 0.f, 0.f};
    int i0 = kc * 64;
    for (int r = 0; r < 64; ++r) {
      int i = i0 + r;
      float xv = (i < DD) ? z[i] : h[i - DD];
      float4 w4 = *(const float4*)(W + (size_t)i * DD + j);
      a.x += xv * w4.x; a.y += xv * w4.y; a.z += xv * w4.z; a.w += xv * w4.w;
    }
    atomicAdd(&acc[j + 0], a.x);
    atomicAdd(&acc[j + 1], a.y);
    atomicAdd(&acc[j + 2], a.z);
    atomicAdd(&acc[j + 3], a.w);
  }
}

// =====================================================================
// MEGA2: blocks [0,256): per-block top-8 of its 256 sims -> candidates
//        blocks [256,264): finalize u = tanh(qacc+bq)*ws, gate hidden,
//                          scalar accs g_acc = hg.wg2, bcu = bc.u
// =====================================================================
__global__ __launch_bounds__(256) void k_mega2(
    const float* __restrict__ bq, const float* __restrict__ wsv,
    const float* __restrict__ bg1, const float* __restrict__ wg2,
    const float* __restrict__ bc, float* __restrict__ ws)
{
  int bid = blockIdx.x;
  int tid = threadIdx.x;
  if (bid < 256) {
    int lane = tid & 63, wv = tid >> 6;
    int gi = bid * 256 + tid;
    float myv = ws[WS_SIMS + gi];
    int   myi = gi;
    float sel_v = -INFINITY; int sel_i = 0x7fffffff;
    // wave top-8 via 8 argmax butterfly passes
    for (int p = 0; p < 8; ++p) {
      float bv = myv; int bi2 = myi;
      for (int off = 32; off > 0; off >>= 1) {
        float ov = __shfl_xor(bv, off);
        int   oi = __shfl_xor(bi2, off);
        if (ov > bv || (ov == bv && oi < bi2)) { bv = ov; bi2 = oi; }
      }
      if (myi == bi2) myv = -INFINITY;      // owner removes
      if (lane == p) { sel_v = bv; sel_i = bi2; }
    }
    __shared__ float lv[32];
    __shared__ int   li[32];
    if (lane < 8) { lv[wv * 8 + lane] = sel_v; li[wv * 8 + lane] = sel_i; }
    __syncthreads();
    if (wv == 0) {  // wave 0 merges 32 candidates -> block top-8
      float cv = (lane < 32) ? lv[lane] : -INFINITY;
      int   ci = (lane < 32) ? li[lane] : 0x7fffffff;
      float s2v = -INFINITY; int s2i = 0x7fffffff;
      for (int p = 0; p < 8; ++p) {
        float bv = cv; int bi2 = ci;
        for (int off = 32; off > 0; off >>= 1) {
          float ov = __shfl_xor(bv, off);
          int   oi = __shfl_xor(bi2, off);
          if (ov > bv || (ov == bv && oi < bi2)) { bv = ov; bi2 = oi; }
        }
        if (ci == bi2) cv = -INFINITY;
        if (lane == p) { s2v = bv; s2i = bi2; }
      }
      if (lane < 8) {
        ws[WS_CVAL + bid * 8 + lane] = s2v;
        ((int*)ws)[WS_CIDX + bid * 8 + lane] = s2i;
      }
    }
  } else {
    int i = (bid - 256) * 256 + tid;   // i in [0,2048)
    float qv  = tanhf(ws[WS_QACC + i] + bq[i]);
    float uu  = qv * wsv[i];
    ws[WS_U + i] = uu;
    float hgt = tanhf(ws[WS_HGACC + i] + bg1[i]);
    float pg = hgt * wg2[i];
    float pb = bc[i] * uu;
    for (int off = 32; off > 0; off >>= 1) {
      pg += __shfl_down(pg, off);
      pb += __shfl_down(pb, off);
    }
    if ((tid & 63) == 0) {
      atomicAdd(&ws[WS_GACC], pg);
      atomicAdd(&ws[WS_BCU], pb);
    }
  }
}

// =====================================================================
// MEGA3: blocks [0,512): v[row] = Wc[row,:] . u   (wave per row)
//        block 512:      merge 2048 candidates -> global top-8 indices
// =====================================================================
__global__ __launch_bounds__(256) void k_mega3(
    const float* __restrict__ Wc, float* __restrict__ ws)
{
  int bid = blockIdx.x;
  int tid = threadIdx.x;
  if (bid < 512) {
    int wv = tid >> 6, lane = tid & 63;
    int row = bid * 4 + wv;
    const float4* wr = (const float4*)(Wc + (size_t)row * DD);
    const float4* u4 = (const float4*)(ws + WS_U);
    float acc = 0.f;
#pragma unroll
    for (int it = 0; it < 8; ++it) {
      float4 w4 = wr[lane + 64 * it];
      float4 uu = u4[lane + 64 * it];
      acc += w4.x * uu.x + w4.y * uu.y + w4.z * uu.z + w4.w * uu.w;
    }
    for (int off = 32; off > 0; off >>= 1) acc += __shfl_down(acc, off);
    if (lane == 0) ws[WS_V + row] = acc;
  } else {
    int lane = tid & 63, wv = tid >> 6;
    float cv[8]; int ci[8];
#pragma unroll
    for (int p = 0; p < 8; ++p) {
      cv[p] = ws[WS_CVAL + tid + 256 * p];
      ci[p] = ((const int*)ws)[WS_CIDX + tid + 256 * p];
    }
    __shared__ float sv[4];
    __shared__ int   si[4];
    __shared__ int   wii;
    for (int k = 0; k < 8; ++k) {
      float bv = -INFINITY; int bi = 0x7fffffff;
#pragma unroll
      for (int p = 0; p < 8; ++p)
        if (cv[p] > bv || (cv[p] == bv && ci[p] < bi)) { bv = cv[p]; bi = ci[p]; }
      for (int off = 32; off > 0; off >>= 1) {
        float ov = __shfl_xor(bv, off);
        int   oi = __shfl_xor(bi, off);
        if (ov > bv || (ov == bv && oi < bi)) { bv = ov; bi = oi; }
      }
      if (lane == 0) { sv[wv] = bv; si[wv] = bi; }
      __syncthreads();
      if (tid == 0) {
        float fb = sv[0]; int fi = si[0];
        for (int w2 = 1; w2 < 4; ++w2)
          if (sv[w2] > fb || (sv[w2] == fb && si[w2] < fi)) { fb = sv[w2]; fi = si[w2]; }
        ((int*)ws)[WS_TOPIDX + k] = fi;
        wii = fi;
      }
      __syncthreads();
      int w = wii;
#pragma unroll
      for (int p = 0; p < 8; ++p)
        if (ci[p] == w) cv[p] = -INFINITY;
    }
  }
}

// =====================================================================
// Build C (12 rows) + logits[m] = C[m].v + bc.u + bs
// blocks 0..7: protos = mem_bank[topidx[m]] (un-normalized originals)
// blocks 8..11: dreams = normalize(0.7*noise + 0.3*z)
// =====================================================================
__global__ __launch_bounds__(256) void k_buildc(
    const float* __restrict__ z, const float* __restrict__ mem,
    const float* __restrict__ noise, const float* __restrict__ bs,
    float* __restrict__ ws)
{
  int m = blockIdx.x, tid = threadIdx.x;
  int lane = tid & 63, wv = tid >> 6;
  const float4* v4 = (const float4*)(ws + WS_V);
  float4* crow = (float4*)(ws + WS_CMAT + m * DD);
  __shared__ float red[4];
  float acc = 0.f;
  if (m < 8) {
    int row = ((const int*)ws)[WS_TOPIDX + m];
    const float4* src = (const float4*)(mem + (size_t)row * DD);
#pragma unroll
    for (int it = 0; it < 2; ++it) {
      int p = tid + 256 * it;
      float4 s4 = src[p];
      crow[p] = s4;
      float4 vv = v4[p];
      acc += s4.x * vv.x + s4.y * vv.y + s4.z * vv.z + s4.w * vv.w;
    }
  } else {
    const float4* nz = (const float4*)(noise + (size_t)(m - 8) * DD);
    const float4* z4 = (const float4*)z;
    float4 d[2];
    float ss = 0.f;
#pragma unroll
    for (int it = 0; it < 2; ++it) {
      int p = tid + 256 * it;
      float4 n4 = nz[p], zz = z4[p];
      d[it].x = 0.7f * n4.x + 0.3f * zz.x;
      d[it].y = 0.7f * n4.y + 0.3f * zz.y;
      d[it].z = 0.7f * n4.z + 0.3f * zz.z;
      d[it].w = 0.7f * n4.w + 0.3f * zz.w;
      ss += d[it].x * d[it].x + d[it].y * d[it].y + d[it].z * d[it].z + d[it].w * d[it].w;
    }
    for (int off = 32; off > 0; off >>= 1) ss += __shfl_down(ss, off);
    if (lane == 0) red[wv] = ss;
    __syncthreads();
    float tot = red[0] + red[1] + red[2] + red[3];
    float rn = 1.f / fmaxf(sqrtf(tot), 1e-12f);
    __syncthreads();   // red reused below
#pragma unroll
    for (int it = 0; it < 2; ++it) {
      int p = tid + 256 * it;
      float4 c4 = { d[it].x * rn, d[it].y * rn, d[it].z * rn, d[it].w * rn };
      crow[p] = c4;
      float4 vv = v4[p];
      acc += c4.x * vv.x + c4.y * vv.y + c4.z * vv.z + c4.w * vv.w;
    }
  }
  for (int off = 32; off > 0; off >>= 1) acc += __shfl_down(acc, off);
  __syncthreads();
  if (lane == 0) red[wv] = acc;
  __syncthreads();
  if (tid == 0)
    ws[WS_LOGITS + m] = red[0] + red[1] + red[2] + red[3] + ws[WS_BCU] + bs[0];
}

// =====================================================================
// Wm GEMV with inline softmax + on-the-fly s_raw:
// macc[j] += sum_i s_raw[i] * Wm[i][j], s_raw[i] = sum_m attn[m]*C[m][i]
// grid 256: jt in {0,1} (1024-col tiles), kc in [0,128) (16-row chunks)
// =====================================================================
__global__ __launch_bounds__(256) void k_wm(
    const float* __restrict__ Wm, float* __restrict__ ws)
{
  int g = blockIdx.x, tid = threadIdx.x;
  int jt = g & 1, kc = g >> 1;
  float l[12];
#pragma unroll
  for (int m2 = 0; m2 < 12; ++m2) l[m2] = ws[WS_LOGITS + m2];
  float mx = l[0];
#pragma unroll
  for (int m2 = 1; m2 < 12; ++m2) mx = fmaxf(mx, l[m2]);
  float s = 0.f;
#pragma unroll
  for (int m2 = 0; m2 < 12; ++m2) { l[m2] = expf(l[m2] - mx); s += l[m2]; }
  float inv = 1.f / s;
  int j = jt * 1024 + tid * 4;
  float4 a = {0.f, 0.f, 0.f, 0.f};
  for (int r = 0; r < 16; ++r) {
    int i = kc * 16 + r;
    float sr = 0.f;
#pragma unroll
    for (int m2 = 0; m2 < 12; ++m2) sr += l[m2] * ws[WS_CMAT + m2 * DD + i];
    sr *= inv;
    float4 w4 = *(const float4*)(Wm + (size_t)i * DD + j);
    a.x += sr * w4.x; a.y += sr * w4.y; a.z += sr * w4.z; a.w += sr * w4.w;
  }
  atomicAdd(&ws[WS_MACC + j + 0], a.x);
  atomicAdd(&ws[WS_MACC + j + 1], a.y);
  atomicAdd(&ws[WS_MACC + j + 2], a.z);
  atomicAdd(&ws[WS_MACC + j + 3], a.w);
}

// =====================================================================
// Final: out[j] = sigmoid(gacc + bg2) * tanh(macc[j] + bm[j])
// =====================================================================
__global__ __launch_bounds__(256) void k_final(
    const float* __restrict__ bm, const float* __restrict__ bg2,
    float* __restrict__ out, const float* __restrict__ ws)
{
  int j = blockIdx.x * 256 + threadIdx.x;
  float gv = 1.f / (1.f + expf(-(ws[WS_GACC] + bg2[0])));
  out[j] = gv * tanhf(ws[WS_MACC + j] + bm[j]);
}

extern "C" void kernel_launch(void* const* d_in, const int* in_sizes, int n_in,
                              void* d_out, int out_size, void* d_ws, size_t ws_size,
                              hipStream_t stream) {
  const float* z    = (const float*)d_in[0];
  const float* h    = (const float*)d_in[1];
  const float* mem  = (const float*)d_in[2];
  const float* noise= (const float*)d_in[3];
  const float* Wq   = (const float*)d_in[4];
  const float* bq   = (const float*)d_in[5];
  const float* Wc   = (const float*)d_in[6];
  const float* bc   = (const float*)d_in[7];
  const float* wsv  = (const float*)d_in[8];
  const float* bs   = (const float*)d_in[9];
  const float* Wm   = (const float*)d_in[10];
  const float* bm   = (const float*)d_in[11];
  const float* Wg1  = (const float*)d_in[12];
  const float* bg1  = (const float*)d_in[13];
  const float* wg2  = (const float*)d_in[14];
  const float* bg2  = (const float*)d_in[15];
  float* ws  = (float*)d_ws;
  float* out = (float*)d_out;

  // zero the atomic accumulator region (QACC,HGACC,MACC,GACC,BCU contiguous)
  hipMemsetAsync(ws + WS_QACC, 0, (size_t)(3 * 2048 + 2) * sizeof(float), stream);

  k_mega1 <<<16384 + 256, 256, 0, stream>>>(z, h, mem, Wq, Wg1, ws);
  k_mega2 <<<264,          256, 0, stream>>>(bq, wsv, bg1, wg2, bc, ws);
  k_mega3 <<<513,          256, 0, stream>>>(Wc, ws);
  k_buildc<<<12,           256, 0, stream>>>(z, mem, noise, bs, ws);
  k_wm    <<<256,          256, 0, stream>>>(Wm, ws);
  k_final <<<8,            256, 0, stream>>>(bm, bg2, out, ws);
}

// Round 2
// 787.877 us; speedup vs baseline: 1.0182x; 1.0182x over previous
//
#include <hip/hip_runtime.h>
#include <math.h>

// ---------------- problem constants ----------------
#define DD 2048
#define NBANK 65536

// ---------------- ws layout (float-element offsets, 16-float aligned) -------
constexpr int WS_SIMS   = 0;        // 65536 floats
constexpr int WS_CVAL   = 65536;    // 2048 floats (stage-1 top-8 candidate values)
constexpr int WS_CIDX   = 67584;    // 2048 ints   (candidate indices)
constexpr int WS_TOPIDX = 69632;    // 16 ints     (final top-8 indices)
constexpr int WS_U      = 69648;    // 2048 floats (u = q_vec * ws)
constexpr int WS_V      = 71696;    // 2048 floats (v = Wc @ u)
constexpr int WS_CMAT   = 73744;    // 12*2048 floats (C matrix)
constexpr int WS_LOGITS = 98320;    // 16 floats
// partial-sum buffers (no atomics, no memset needed):
constexpr int WS_QPART  = 98336;    // 64 x 2048  (ctx@Wq split-K partials)
constexpr int WS_HGPART = 229408;   // 64 x 2048  (ctx@Wg1 split-K partials)
constexpr int WS_GPART  = 360480;   // 8 (gate scalar per-block partials)
constexpr int WS_BPART  = 360496;   // 8 (bc.u scalar per-block partials)
constexpr int WS_MPART  = 360512;   // 128 x 2048 (s_raw@Wm split-K partials)

// =====================================================================
// MEGA1: blocks [0,16384): sims[row] = dot(mem[row],z)/||mem[row]||  (wave/row)
//        blocks [16384,16640): split-K GEMV for ctx@Wq / ctx@Wg1 -> partials
// =====================================================================
__global__ __launch_bounds__(256) void k_mega1(
    const float* __restrict__ z, const float* __restrict__ h,
    const float* __restrict__ mem, const float* __restrict__ Wq,
    const float* __restrict__ Wg1, float* __restrict__ ws)
{
  int bid = blockIdx.x;
  int tid = threadIdx.x;
  if (bid < 16384) {
    int wv = tid >> 6, lane = tid & 63;
    int row = bid * 4 + wv;
    const float4* mrow = (const float4*)(mem + (size_t)row * DD);
    const float4* z4   = (const float4*)z;
    float dot = 0.f, ss = 0.f;
#pragma unroll
    for (int it = 0; it < 8; ++it) {
      float4 m4 = mrow[lane + 64 * it];
      float4 zz = z4[lane + 64 * it];
      dot += m4.x * zz.x + m4.y * zz.y + m4.z * zz.z + m4.w * zz.w;
      ss  += m4.x * m4.x + m4.y * m4.y + m4.z * m4.z + m4.w * m4.w;
    }
    for (int off = 32; off > 0; off >>= 1) {
      dot += __shfl_down(dot, off);
      ss  += __shfl_down(ss, off);
    }
    if (lane == 0)
      ws[WS_SIMS + row] = dot / fmaxf(sqrtf(ss), 1e-12f);
  } else {
    int b2 = bid - 16384;
    const float* W = (b2 < 128) ? Wq : Wg1;
    float* part = ws + ((b2 < 128) ? WS_QPART : WS_HGPART);
    int g  = b2 & 127;
    int jt = g & 1;        // 2 j-tiles of 1024 cols
    int kc = g >> 1;       // 64 k-chunks of 64 rows (K = 4096)
    int j  = jt * 1024 + tid * 4;
    float4 a = {0.f, 0.f, 0.f, 0.f};
    int i0 = kc * 64;
    for (int r = 0; r < 64; ++r) {
      int i = i0 + r;
      float xv = (i < DD) ? z[i] : h[i - DD];
      float4 w4 = *(const float4*)(W + (size_t)i * DD + j);
      a.x += xv * w4.x; a.y += xv * w4.y; a.z += xv * w4.z; a.w += xv * w4.w;
    }
    *(float4*)(part + (size_t)kc * DD + j) = a;
  }
}

// =====================================================================
// MEGA2: blocks [0,256): per-block top-8 of its 256 sims -> candidates
//        blocks [256,264): sum split-K partials, u = tanh(qacc+bq)*ws,
//                          gate hidden; per-block scalar partials g/bcu
// =====================================================================
__global__ __launch_bounds__(256) void k_mega2(
    const float* __restrict__ bq, const float* __restrict__ wsv,
    const float* __restrict__ bg1, const float* __restrict__ wg2,
    const float* __restrict__ bc, float* __restrict__ ws)
{
  int bid = blockIdx.x;
  int tid = threadIdx.x;
  if (bid < 256) {
    int lane = tid & 63, wv = tid >> 6;
    int gi = bid * 256 + tid;
    float myv = ws[WS_SIMS + gi];
    int   myi = gi;
    float sel_v = -INFINITY; int sel_i = 0x7fffffff;
    // wave top-8 via 8 argmax butterfly passes
    for (int p = 0; p < 8; ++p) {
      float bv = myv; int bi2 = myi;
      for (int off = 32; off > 0; off >>= 1) {
        float ov = __shfl_xor(bv, off);
        int   oi = __shfl_xor(bi2, off);
        if (ov > bv || (ov == bv && oi < bi2)) { bv = ov; bi2 = oi; }
      }
      if (myi == bi2) myv = -INFINITY;      // owner removes
      if (lane == p) { sel_v = bv; sel_i = bi2; }
    }
    __shared__ float lv[32];
    __shared__ int   li[32];
    if (lane < 8) { lv[wv * 8 + lane] = sel_v; li[wv * 8 + lane] = sel_i; }
    __syncthreads();
    if (wv == 0) {  // wave 0 merges 32 candidates -> block top-8
      float cv = (lane < 32) ? lv[lane] : -INFINITY;
      int   ci = (lane < 32) ? li[lane] : 0x7fffffff;
      float s2v = -INFINITY; int s2i = 0x7fffffff;
      for (int p = 0; p < 8; ++p) {
        float bv = cv; int bi2 = ci;
        for (int off = 32; off > 0; off >>= 1) {
          float ov = __shfl_xor(bv, off);
          int   oi = __shfl_xor(bi2, off);
          if (ov > bv || (ov == bv && oi < bi2)) { bv = ov; bi2 = oi; }
        }
        if (ci == bi2) cv = -INFINITY;
        if (lane == p) { s2v = bv; s2i = bi2; }
      }
      if (lane < 8) {
        ws[WS_CVAL + bid * 8 + lane] = s2v;
        ((int*)ws)[WS_CIDX + bid * 8 + lane] = s2i;
      }
    }
  } else {
    int blk = bid - 256;               // [0,8)
    int i = blk * 256 + tid;           // i in [0,2048)
    int lane = tid & 63, wv = tid >> 6;
    float qacc = 0.f, hacc = 0.f;
#pragma unroll 8
    for (int kc = 0; kc < 64; ++kc) {
      qacc += ws[WS_QPART  + kc * DD + i];
      hacc += ws[WS_HGPART + kc * DD + i];
    }
    float qv  = tanhf(qacc + bq[i]);
    float uu  = qv * wsv[i];
    ws[WS_U + i] = uu;
    float hgt = tanhf(hacc + bg1[i]);
    float pg = hgt * wg2[i];
    float pb = bc[i] * uu;
    for (int off = 32; off > 0; off >>= 1) {
      pg += __shfl_down(pg, off);
      pb += __shfl_down(pb, off);
    }
    __shared__ float rg[4], rb[4];
    if (lane == 0) { rg[wv] = pg; rb[wv] = pb; }
    __syncthreads();
    if (tid == 0) {
      ws[WS_GPART + blk] = rg[0] + rg[1] + rg[2] + rg[3];
      ws[WS_BPART + blk] = rb[0] + rb[1] + rb[2] + rb[3];
    }
  }
}

// =====================================================================
// MEGA3: blocks [0,512): v[row] = Wc[row,:] . u   (wave per row)
//        block 512:      merge 2048 candidates -> global top-8 indices
// =====================================================================
__global__ __launch_bounds__(256) void k_mega3(
    const float* __restrict__ Wc, float* __restrict__ ws)
{
  int bid = blockIdx.x;
  int tid = threadIdx.x;
  if (bid < 512) {
    int wv = tid >> 6, lane = tid & 63;
    int row = bid * 4 + wv;
    const float4* wr = (const float4*)(Wc + (size_t)row * DD);
    const float4* u4 = (const float4*)(ws + WS_U);
    float acc = 0.f;
#pragma unroll
    for (int it = 0; it < 8; ++it) {
      float4 w4 = wr[lane + 64 * it];
      float4 uu = u4[lane + 64 * it];
      acc += w4.x * uu.x + w4.y * uu.y + w4.z * uu.z + w4.w * uu.w;
    }
    for (int off = 32; off > 0; off >>= 1) acc += __shfl_down(acc, off);
    if (lane == 0) ws[WS_V + row] = acc;
  } else {
    int lane = tid & 63, wv = tid >> 6;
    float cv[8]; int ci[8];
#pragma unroll
    for (int p = 0; p < 8; ++p) {
      cv[p] = ws[WS_CVAL + tid + 256 * p];
      ci[p] = ((const int*)ws)[WS_CIDX + tid + 256 * p];
    }
    __shared__ float sv[4];
    __shared__ int   si[4];
    __shared__ int   wii;
    for (int k = 0; k < 8; ++k) {
      float bv = -INFINITY; int bi = 0x7fffffff;
#pragma unroll
      for (int p = 0; p < 8; ++p)
        if (cv[p] > bv || (cv[p] == bv && ci[p] < bi)) { bv = cv[p]; bi = ci[p]; }
      for (int off = 32; off > 0; off >>= 1) {
        float ov = __shfl_xor(bv, off);
        int   oi = __shfl_xor(bi, off);
        if (ov > bv || (ov == bv && oi < bi)) { bv = ov; bi = oi; }
      }
      if (lane == 0) { sv[wv] = bv; si[wv] = bi; }
      __syncthreads();
      if (tid == 0) {
        float fb = sv[0]; int fi = si[0];
        for (int w2 = 1; w2 < 4; ++w2)
          if (sv[w2] > fb || (sv[w2] == fb && si[w2] < fi)) { fb = sv[w2]; fi = si[w2]; }
        ((int*)ws)[WS_TOPIDX + k] = fi;
        wii = fi;
      }
      __syncthreads();
      int w = wii;
#pragma unroll
      for (int p = 0; p < 8; ++p)
        if (ci[p] == w) cv[p] = -INFINITY;
    }
  }
}

// =====================================================================
// Build C (12 rows) + logits[m] = C[m].v + bc.u + bs
// blocks 0..7: protos = mem_bank[topidx[m]] (un-normalized originals)
// blocks 8..11: dreams = normalize(0.7*noise + 0.3*z)
// =====================================================================
__global__ __launch_bounds__(256) void k_buildc(
    const float* __restrict__ z, const float* __restrict__ mem,
    const float* __restrict__ noise, const float* __restrict__ bs,
    float* __restrict__ ws)
{
  int m = blockIdx.x, tid = threadIdx.x;
  int lane = tid & 63, wv = tid >> 6;
  const float4* v4 = (const float4*)(ws + WS_V);
  float4* crow = (float4*)(ws + WS_CMAT + m * DD);
  __shared__ float red[4];
  float acc = 0.f;
  if (m < 8) {
    int row = ((const int*)ws)[WS_TOPIDX + m];
    const float4* src = (const float4*)(mem + (size_t)row * DD);
#pragma unroll
    for (int it = 0; it < 2; ++it) {
      int p = tid + 256 * it;
      float4 s4 = src[p];
      crow[p] = s4;
      float4 vv = v4[p];
      acc += s4.x * vv.x + s4.y * vv.y + s4.z * vv.z + s4.w * vv.w;
    }
  } else {
    const float4* nz = (const float4*)(noise + (size_t)(m - 8) * DD);
    const float4* z4 = (const float4*)z;
    float4 d[2];
    float ss = 0.f;
#pragma unroll
    for (int it = 0; it < 2; ++it) {
      int p = tid + 256 * it;
      float4 n4 = nz[p], zz = z4[p];
      d[it].x = 0.7f * n4.x + 0.3f * zz.x;
      d[it].y = 0.7f * n4.y + 0.3f * zz.y;
      d[it].z = 0.7f * n4.z + 0.3f * zz.z;
      d[it].w = 0.7f * n4.w + 0.3f * zz.w;
      ss += d[it].x * d[it].x + d[it].y * d[it].y + d[it].z * d[it].z + d[it].w * d[it].w;
    }
    for (int off = 32; off > 0; off >>= 1) ss += __shfl_down(ss, off);
    if (lane == 0) red[wv] = ss;
    __syncthreads();
    float tot = red[0] + red[1] + red[2] + red[3];
    float rn = 1.f / fmaxf(sqrtf(tot), 1e-12f);
    __syncthreads();   // red reused below
#pragma unroll
    for (int it = 0; it < 2; ++it) {
      int p = tid + 256 * it;
      float4 c4 = { d[it].x * rn, d[it].y * rn, d[it].z * rn, d[it].w * rn };
      crow[p] = c4;
      float4 vv = v4[p];
      acc += c4.x * vv.x + c4.y * vv.y + c4.z * vv.z + c4.w * vv.w;
    }
  }
  for (int off = 32; off > 0; off >>= 1) acc += __shfl_down(acc, off);
  __syncthreads();
  if (lane == 0) red[wv] = acc;
  __syncthreads();
  if (tid == 0) {
    float bcu = 0.f;
#pragma unroll
    for (int b = 0; b < 8; ++b) bcu += ws[WS_BPART + b];
    ws[WS_LOGITS + m] = red[0] + red[1] + red[2] + red[3] + bcu + bs[0];
  }
}

// =====================================================================
// Wm GEMV with inline softmax + on-the-fly s_raw -> split-K partials:
// mpart[kc][j] = sum_{i in chunk kc} s_raw[i] * Wm[i][j]
// grid 256: jt in {0,1} (1024-col tiles), kc in [0,128) (16-row chunks)
// =====================================================================
__global__ __launch_bounds__(256) void k_wm(
    const float* __restrict__ Wm, float* __restrict__ ws)
{
  int g = blockIdx.x, tid = threadIdx.x;
  int jt = g & 1, kc = g >> 1;
  float l[12];
#pragma unroll
  for (int m2 = 0; m2 < 12; ++m2) l[m2] = ws[WS_LOGITS + m2];
  float mx = l[0];
#pragma unroll
  for (int m2 = 1; m2 < 12; ++m2) mx = fmaxf(mx, l[m2]);
  float s = 0.f;
#pragma unroll
  for (int m2 = 0; m2 < 12; ++m2) { l[m2] = expf(l[m2] - mx); s += l[m2]; }
  float inv = 1.f / s;
  int j = jt * 1024 + tid * 4;
  float4 a = {0.f, 0.f, 0.f, 0.f};
  for (int r = 0; r < 16; ++r) {
    int i = kc * 16 + r;
    float sr = 0.f;
#pragma unroll
    for (int m2 = 0; m2 < 12; ++m2) sr += l[m2] * ws[WS_CMAT + m2 * DD + i];
    sr *= inv;
    float4 w4 = *(const float4*)(Wm + (size_t)i * DD + j);
    a.x += sr * w4.x; a.y += sr * w4.y; a.z += sr * w4.z; a.w += sr * w4.w;
  }
  *(float4*)(ws + WS_MPART + (size_t)kc * DD + j) = a;
}

// =====================================================================
// Final: out[j] = sigmoid(sum gpart + bg2) * tanh(sum_kc mpart[kc][j] + bm[j])
// =====================================================================
__global__ __launch_bounds__(256) void k_final(
    const float* __restrict__ bm, const float* __restrict__ bg2,
    float* __restrict__ out, const float* __restrict__ ws)
{
  int j = blockIdx.x * 256 + threadIdx.x;
  float gs = 0.f;
#pragma unroll
  for (int b = 0; b < 8; ++b) gs += ws[WS_GPART + b];
  float gv = 1.f / (1.f + expf(-(gs + bg2[0])));
  float m = 0.f;
#pragma unroll 16
  for (int kc = 0; kc < 128; ++kc) m += ws[WS_MPART + kc * DD + j];
  out[j] = gv * tanhf(m + bm[j]);
}

extern "C" void kernel_launch(void* const* d_in, const int* in_sizes, int n_in,
                              void* d_out, int out_size, void* d_ws, size_t ws_size,
                              hipStream_t stream) {
  const float* z    = (const float*)d_in[0];
  const float* h    = (const float*)d_in[1];
  const float* mem  = (const float*)d_in[2];
  const float* noise= (const float*)d_in[3];
  const float* Wq   = (const float*)d_in[4];
  const float* bq   = (const float*)d_in[5];
  const float* Wc   = (const float*)d_in[6];
  const float* bc   = (const float*)d_in[7];
  const float* wsv  = (const float*)d_in[8];
  const float* bs   = (const float*)d_in[9];
  const float* Wm   = (const float*)d_in[10];
  const float* bm   = (const float*)d_in[11];
  const float* Wg1  = (const float*)d_in[12];
  const float* bg1  = (const float*)d_in[13];
  const float* wg2  = (const float*)d_in[14];
  const float* bg2  = (const float*)d_in[15];
  float* ws  = (float*)d_ws;
  float* out = (float*)d_out;

  k_mega1 <<<16384 + 256, 256, 0, stream>>>(z, h, mem, Wq, Wg1, ws);
  k_mega2 <<<264,          256, 0, stream>>>(bq, wsv, bg1, wg2, bc, ws);
  k_mega3 <<<513,          256, 0, stream>>>(Wc, ws);
  k_buildc<<<12,           256, 0, stream>>>(z, mem, noise, bs, ws);
  k_wm    <<<256,          256, 0, stream>>>(Wm, ws);
  k_final <<<8,            256, 0, stream>>>(bm, bg2, out, ws);
}